// Round 7
// baseline (27668.558 us; speedup 1.0000x reference)
//
#include <hip/hip_runtime.h>
#include <hip/hip_bf16.h>
#include <stdint.h>

typedef unsigned short ushort_t;
typedef unsigned long long u64_t;

#define H   512
#define E   128
#define NC  27
#define NE  28
#define B   256
#define T   512
#define FH  2048        // 4*H
#define NPH (T + 2)     // phases 0..T+1
#define NBLK 224        // 64 L0 + 128 L1 + 32 OUT
#define NPROD 192       // L0+L1 blocks are producers
#define BHs (B * H)
#define LDS_BYTES (97 * 1024)
#define IDS_OFF (96 * 1024)

// counter array layout (ints)
#define CNTA_WORDS (NPH * 64)           // barrier A: [q][16 cells * 4 stride]
#define CNTB_WORDS ((NPH + 1) * 64)     // barrier B: [q+1][16 cells * 4 stride]
#define ARR_OFF    (CNTA_WORDS + CNTB_WORDS)
#define START_OFF  (ARR_OFF + 64)
#define CNT_TOTAL  (START_OFF + 64)

typedef __bf16 bf16x8 __attribute__((ext_vector_type(8)));
typedef float  f32x4  __attribute__((ext_vector_type(4)));

__device__ __forceinline__ ushort_t f2b(float x) {
    uint32_t u = __float_as_uint(x);
    uint32_t r = (u + 0x7FFFu + ((u >> 16) & 1u)) >> 16;
    return (ushort_t)r;
}
__device__ __forceinline__ float sigm(float x) {
    return 1.f / (1.f + __expf(-x));
}
__device__ __forceinline__ bf16x8 ldg8(const ushort_t* p) {
    return *(const bf16x8*)p;       // plain cached load
}
// LLC-coherent 16B load (bypasses L1/L2) — used only by the mirror pull
__device__ __forceinline__ bf16x8 ldc16(const ushort_t* p) {
    union { u64_t q[2]; bf16x8 v; } u;
    u.q[0] = __hip_atomic_load((const u64_t*)p,       __ATOMIC_RELAXED, __HIP_MEMORY_SCOPE_AGENT);
    u.q[1] = __hip_atomic_load(((const u64_t*)p) + 1, __ATOMIC_RELAXED, __HIP_MEMORY_SCOPE_AGENT);
    return u.v;
}
// write-through agent store — LLC-visible, no dirty L2 line
__device__ __forceinline__ void stc2(ushort_t* p, ushort_t v) {
    __hip_atomic_store(p, v, __ATOMIC_RELAXED, __HIP_MEMORY_SCOPE_AGENT);
}
__device__ __forceinline__ void stc4f(float* p, float v) {
    __hip_atomic_store(p, v, __ATOMIC_RELAXED, __HIP_MEMORY_SCOPE_AGENT);
}

// ---------------- setup kernels ----------------

__global__ void k_init(int* __restrict__ cnt) {
    for (int i = blockIdx.x * blockDim.x + threadIdx.x; i < CNT_TOTAL;
         i += gridDim.x * blockDim.x) cnt[i] = 0;
}

// G0 layout: [cell][token][j][gate] f32
__global__ void k_g0(const float* __restrict__ embed, const float* __restrict__ Wih0,
                     const float* __restrict__ bih, const float* __restrict__ bhh,
                     float* __restrict__ G0, float* __restrict__ bias1) {
    int i = blockIdx.x * blockDim.x + threadIdx.x;
    if (i < 2 * NE * FH) {
        int d = i / (NE * FH);
        int rem = i % (NE * FH);
        int e = rem / FH;
        int n = rem % FH;
        int g = n >> 9, j = n & 511;
        const float* er = embed + (size_t)e * E;
        const float* wr = Wih0 + ((size_t)d * FH + n) * E;
        float s = 0.f;
        #pragma unroll 8
        for (int k = 0; k < E; ++k) s += er[k] * wr[k];
        G0[(((size_t)d * NE + e) * 512 + j) * 4 + g]
            = s + bih[(size_t)d * FH + n] + bhh[(size_t)d * FH + n];
    }
    if (i < 2 * FH) bias1[i] = bih[2 * FH + i] + bhh[2 * FH + i];
}

__global__ void k_state(const float* __restrict__ h0, ushort_t* __restrict__ hb16) {
    int i = blockIdx.x * blockDim.x + threadIdx.x;
    if (i >= 4 * B * H) return;
    int cell = i / (B * H);
    int rem  = i % (B * H);
    hb16[((size_t)(cell * 2 + 1)) * (B * H) + rem] = f2b(h0[i]);   // parity 1 = step -1
}

__global__ void k_tokT(const int* __restrict__ tok, int* __restrict__ tokT) {
    int i = blockIdx.x * blockDim.x + threadIdx.x;
    if (i < B * T) {
        int b = i / T, t = i % T;
        tokT[(size_t)t * B + b] = tok[i];
    }
}

__global__ void k_len(const int* __restrict__ lens, float* __restrict__ out_len) {
    int i = threadIdx.x;
    if (i < B) out_len[i] = (float)lens[i];
}

// ---------------- phase boundary ----------------
struct SyncCtx {
    int tid, bid, isProd, slot, ns;
    int* cntA;
    int* cntB;
    const ushort_t* hbg;
    ushort_t* hmirX;    // this XCD's mirror
};

__device__ __forceinline__ void boundary(const SyncCtx& s, int q) {
    __syncthreads();                          // drains producer sc-stores (vmcnt0)
    // barrier A: wait for all producers of phase q
    if (q >= 0 && s.tid == 0) {
        int* pc = s.cntA + q * 64;
        if (s.isProd)
            __hip_atomic_fetch_add(pc + (s.bid & 15) * 4, 1,
                                   __ATOMIC_RELAXED, __HIP_MEMORY_SCOPE_AGENT);
        int tot;
        do {
            tot = 0;
            #pragma unroll
            for (int c = 0; c < 16; ++c)
                tot += __hip_atomic_load(pc + c * 4, __ATOMIC_RELAXED, __HIP_MEMORY_SCOPE_AGENT);
            if (tot < NPROD) __builtin_amdgcn_s_sleep(2);
        } while (tot < NPROD);
    }
    __syncthreads();
    __builtin_amdgcn_sched_barrier(0);
    // pull fresh h parities from LLC into this XCD's mirror (plain stores -> local L2)
    {
        const int parA = (q < 0) ? 1 : (q & 1);         // cells 0,1 written during phase q
        const int parB = (q < 0) ? 1 : ((q + 1) & 1);   // cells 2,3 written during phase q
        for (int sl = s.slot; sl < 32; sl += s.ns) {
            int cell = sl >> 3, rg = sl & 7;
            int par = (cell < 2) ? parA : parB;
            size_t off = (size_t)(cell * 2 + par) * BHs + (size_t)rg * 32 * H + s.tid * 32;
            bf16x8 v0 = ldc16(s.hbg + off);
            bf16x8 v1 = ldc16(s.hbg + off + 8);
            bf16x8 v2 = ldc16(s.hbg + off + 16);
            bf16x8 v3 = ldc16(s.hbg + off + 24);
            ushort_t* d = s.hmirX + off;
            *(bf16x8*)(d)      = v0;
            *(bf16x8*)(d + 8)  = v1;
            *(bf16x8*)(d + 16) = v2;
            *(bf16x8*)(d + 24) = v3;
        }
    }
    __syncthreads();                          // drains pull stores into local L2
    // barrier B: all blocks done pulling
    if (s.tid == 0) {
        int* pb = s.cntB + (q + 1) * 64;
        __hip_atomic_fetch_add(pb + (s.bid & 15) * 4, 1,
                               __ATOMIC_RELAXED, __HIP_MEMORY_SCOPE_AGENT);
        int tot;
        do {
            tot = 0;
            #pragma unroll
            for (int c = 0; c < 16; ++c)
                tot += __hip_atomic_load(pb + c * 4, __ATOMIC_RELAXED, __HIP_MEMORY_SCOPE_AGENT);
            if (tot < NBLK) __builtin_amdgcn_s_sleep(2);
        } while (tot < NBLK);
    }
    __syncthreads();
    asm volatile("buffer_inv" ::: "memory");  // L1-only: refetch mirror from local L2
    __builtin_amdgcn_sched_barrier(0);
}

// Phase p: L0 step t=p (p<T); L1 step s=p-1 (1<=p<=T); OUT logits t2=p-2 (p>=2).
// hb16/hmir: [cell][parity][B][H] bf16, parity(step)=step&1.
__global__ __launch_bounds__(512, 2) void k_persist(
    const float* __restrict__ Whh, const float* __restrict__ Wih1,
    const float* __restrict__ G0, const float* __restrict__ bias1,
    const float* __restrict__ c0, ushort_t* __restrict__ hb16,
    ushort_t* hmir,
    const int* __restrict__ tokT, const int* __restrict__ lens,
    const float* __restrict__ Wout, const float* __restrict__ bout,
    float* __restrict__ out, int* __restrict__ cntBase)
{
    extern __shared__ char smem[];
    const int bid = blockIdx.x;
    const int tid = threadIdx.x;
    const int lane = tid & 63, wave = tid >> 6;
    const int lrow = lane & 15, kg = lane >> 4;
    const int row0 = wave * 32;
    const int sw16 = (lrow & 7) << 4;

    int* cntA      = cntBase;
    int* cntB      = cntBase + CNTA_WORDS;
    int* xcdArrive = cntBase + ARR_OFF;
    int* startCnt  = cntBase + START_OFF;

    // ---- identity: physical XCD + dense arrival slot on that XCD ----
    int xcc;
    asm volatile("s_getreg_b32 %0, hwreg(HW_REG_XCC_ID)" : "=s"(xcc));
    xcc &= 7;
    int* ids = (int*)(smem + IDS_OFF);
    if (tid == 0) {
        int slot = __hip_atomic_fetch_add(xcdArrive + xcc * 8, 1,
                                          __ATOMIC_RELAXED, __HIP_MEMORY_SCOPE_AGENT);
        ids[0] = xcc;
        ids[1] = slot;          // consuming slot forces the RMW to complete
    }

    // ---- one-time: stage weights into LDS (f32 -> bf16, XOR-swizzled) ----
    if (bid < 64) {
        const int cell = bid >> 5, jt = bid & 31, j0 = jt * 16;
        const float* Wsrc = Whh + (size_t)cell * FH * H;
        for (int r = wave; r < 64; r += 8) {
            int grow = (r >> 4) * 512 + j0 + (r & 15);
            const float* src = Wsrc + (size_t)grow * H;
            int sw = (r & 7) << 4;
            for (int c = lane; c < H; c += 64) {
                int byte = ((r * H + c) * 2) ^ sw;
                *(ushort_t*)(smem + byte) = f2b(src[c]);
            }
        }
    } else if (bid < 192) {
        const int q = bid - 64, cell = 2 + (q >> 6), jt = q & 63, j0 = jt * 8;
        const float* Wi = Wih1 + (size_t)(cell - 2) * FH * (2 * H);
        const float* Wh = Whh + (size_t)cell * FH * H;
        for (int r = wave; r < 32; r += 8) {
            int grow = (r >> 3) * 512 + j0 + (r & 7);
            const float* si = Wi + (size_t)grow * (2 * H);
            const float* sh = Wh + (size_t)grow * H;
            int sw = (r & 7) << 4;
            for (int c = lane; c < 1536; c += 64) {
                float v = (c < 1024) ? si[c] : sh[c - 1024];
                int byte = ((r * 1536 + c) * 2) ^ sw;
                *(ushort_t*)(smem + byte) = f2b(v);
            }
        }
    } else {
        for (int r = wave; r < NC; r += 8) {
            const float* src = Wout + (size_t)r * (2 * H);
            int sw = (r & 7) << 4;
            for (int c = lane; c < 2 * H; c += 64) {
                int byte = ((r * (2 * H) + c) * 2) ^ sw;
                *(ushort_t*)(smem + byte) = f2b(src[c]);
            }
        }
    }
    __syncthreads();

    // ---- startup rendezvous: all arrival RMWs complete -> ns final ----
    if (tid == 0) {
        __hip_atomic_fetch_add(startCnt + (bid & 15) * 4, 1,
                               __ATOMIC_RELAXED, __HIP_MEMORY_SCOPE_AGENT);
        int tot;
        do {
            tot = 0;
            #pragma unroll
            for (int c = 0; c < 16; ++c)
                tot += __hip_atomic_load(startCnt + c * 4, __ATOMIC_RELAXED, __HIP_MEMORY_SCOPE_AGENT);
            if (tot < NBLK) __builtin_amdgcn_s_sleep(2);
        } while (tot < NBLK);
        ids[2] = __hip_atomic_load(xcdArrive + xcc * 8, __ATOMIC_RELAXED, __HIP_MEMORY_SCOPE_AGENT);
    }
    __syncthreads();

    SyncCtx sc;
    sc.tid = tid; sc.bid = bid; sc.isProd = (bid < NPROD);
    sc.slot = ids[1]; sc.ns = ids[2];
    sc.cntA = cntA; sc.cntB = cntB;
    sc.hbg = hb16;
    sc.hmirX = hmir + (size_t)ids[0] * 8 * BHs;
    const ushort_t* hbloc = sc.hmirX;   // consumers read this XCD's mirror

    boundary(sc, -1);                   // prime mirrors with initial h (parity 1)

    if (bid < 64) {
        // ================= layer 0 =================
        const int cell = bid >> 5, jt = bid & 31, j0 = jt * 16;
        const int j = j0 + lrow;
        const size_t ro = (size_t)(row0 + lrow) * H + kg * 8;

        float cv[8];
        #pragma unroll
        for (int i = 0; i < 8; ++i) {
            int bb = row0 + (i >> 2) * 16 + kg * 4 + (i & 3);
            cv[i] = c0[((size_t)cell * B + bb) * H + j];
        }

        for (int p = 0; p < NPH; ++p) {
            if (p < T) {
                const int parR = (p + 1) & 1, parW = p & 1;
                const ushort_t* ar0 = hbloc + (size_t)(cell * 2 + parR) * BHs + ro;
                const ushort_t* ar1 = ar0 + (size_t)16 * H;

                bf16x8 rb0[8], rb1[8];
                #pragma unroll
                for (int q = 0; q < 8; ++q) {
                    rb0[q] = ldg8(ar0 + q * 32);
                    rb1[q] = ldg8(ar1 + q * 32);
                }

                int tkv[8];
                #pragma unroll
                for (int i = 0; i < 8; ++i) {
                    int bb = row0 + (i >> 2) * 16 + kg * 4 + (i & 3);
                    tkv[i] = tokT[(size_t)p * B + bb];
                }
                f32x4 g0v[8];
                #pragma unroll
                for (int i = 0; i < 8; ++i)
                    g0v[i] = *(const f32x4*)(G0 + (((size_t)cell * NE + tkv[i]) * 512 + j) * 4);

                f32x4 acc[2][4];
                #pragma unroll
                for (int m = 0; m < 2; ++m)
                    #pragma unroll
                    for (int g = 0; g < 4; ++g) acc[m][g] = (f32x4){0.f, 0.f, 0.f, 0.f};

                #pragma unroll
                for (int t = 0; t < 16; ++t) {
                    bf16x8 a0 = rb0[t & 7];
                    bf16x8 a1 = rb1[t & 7];
                    if (t + 8 < 16) {
                        rb0[t & 7] = ldg8(ar0 + (t + 8) * 32);
                        rb1[t & 7] = ldg8(ar1 + (t + 8) * 32);
                    }
                    int cb = (kg * 16 + t * 64) ^ sw16;
                    #pragma unroll
                    for (int g = 0; g < 4; ++g) {
                        bf16x8 bb = *(const bf16x8*)(smem + (g * 16 + lrow) * 1024 + cb);
                        acc[0][g] = __builtin_amdgcn_mfma_f32_16x16x32_bf16(a0, bb, acc[0][g], 0, 0, 0);
                        acc[1][g] = __builtin_amdgcn_mfma_f32_16x16x32_bf16(a1, bb, acc[1][g], 0, 0, 0);
                    }
                }

                #pragma unroll
                for (int i = 0; i < 8; ++i) {
                    int mf = i >> 2, r = i & 3;
                    int bb = row0 + mf * 16 + kg * 4 + r;
                    float gi = acc[mf][0][r] + g0v[i][0];
                    float gf = acc[mf][1][r] + g0v[i][1];
                    float gg = acc[mf][2][r] + g0v[i][2];
                    float go = acc[mf][3][r] + g0v[i][3];
                    float ii = sigm(gi), ff = sigm(gf), oo = sigm(go);
                    float tg = tanhf(gg);
                    float cn = ff * cv[i] + ii * tg;
                    cv[i] = cn;
                    float hn = oo * tanhf(cn);
                    stc2(&hb16[((size_t)(cell * 2 + parW) * B + bb) * H + j], f2b(hn));
                }
            }
            if (p < NPH - 1) boundary(sc, p);
        }
    } else if (bid < 192) {
        // ================= layer 1 =================
        const int q = bid - 64, cell = 2 + (q >> 6), jt = q & 63, j0 = jt * 8;
        const int cc = lrow;
        const int jj = j0 + (cc & 7);
        const int mfS = cc >> 3;
        const size_t ro = (size_t)(row0 + lrow) * H + kg * 8;

        float b1v[4];
        #pragma unroll
        for (int g = 0; g < 4; ++g) b1v[g] = bias1[(size_t)(cell - 2) * FH + g * 512 + jj];

        float cv[4];
        #pragma unroll
        for (int r = 0; r < 4; ++r) {
            int bb = row0 + mfS * 16 + kg * 4 + r;
            cv[r] = c0[((size_t)cell * B + bb) * H + jj];
        }

        for (int p = 0; p < NPH; ++p) {
            if (p >= 1 && p <= T) {
                const int parY  = (p + 1) & 1;
                const int parR2 = p & 1;
                const int parW  = (p + 1) & 1;
                const ushort_t* base0 = hbloc + (size_t)(0 * 2 + parY) * BHs + ro;
                const ushort_t* base1 = hbloc + (size_t)(1 * 2 + parY) * BHs + ro;
                const ushort_t* base2 = hbloc + (size_t)(cell * 2 + parR2) * BHs + ro;

                bf16x8 rb0[8], rb1[8];
                #pragma unroll
                for (int qq = 0; qq < 8; ++qq) {
                    rb0[qq] = ldg8(base0 + qq * 32);
                    rb1[qq] = ldg8(base0 + (size_t)16 * H + qq * 32);
                }

                f32x4 acc[2][2];
                #pragma unroll
                for (int m = 0; m < 2; ++m)
                    #pragma unroll
                    for (int n = 0; n < 2; ++n) acc[m][n] = (f32x4){0.f, 0.f, 0.f, 0.f};

                #pragma unroll
                for (int t = 0; t < 48; ++t) {
                    bf16x8 a0 = rb0[t & 7];
                    bf16x8 a1 = rb1[t & 7];
                    int tn = t + 8;
                    if (tn < 48) {
                        const ushort_t* bp = (tn < 16) ? base0 : (tn < 32) ? base1 : base2;
                        int off = (tn & 15) * 32;
                        rb0[t & 7] = ldg8(bp + off);
                        rb1[t & 7] = ldg8(bp + (size_t)16 * H + off);
                    }
                    int cb = (t * 64 + kg * 16) ^ sw16;
                    bf16x8 b0 = *(const bf16x8*)(smem + lrow * 3072 + cb);
                    bf16x8 b1 = *(const bf16x8*)(smem + (16 + lrow) * 3072 + cb);
                    acc[0][0] = __builtin_amdgcn_mfma_f32_16x16x32_bf16(a0, b0, acc[0][0], 0, 0, 0);
                    acc[0][1] = __builtin_amdgcn_mfma_f32_16x16x32_bf16(a0, b1, acc[0][1], 0, 0, 0);
                    acc[1][0] = __builtin_amdgcn_mfma_f32_16x16x32_bf16(a1, b0, acc[1][0], 0, 0, 0);
                    acc[1][1] = __builtin_amdgcn_mfma_f32_16x16x32_bf16(a1, b1, acc[1][1], 0, 0, 0);
                }

                #pragma unroll
                for (int r = 0; r < 4; ++r) {
                    float a00 = acc[0][0][r], a01 = acc[0][1][r];
                    float a10 = acc[1][0][r], a11 = acc[1][1][r];
                    float e00 = __shfl_xor(a00, 8);
                    float e01 = __shfl_xor(a01, 8);
                    float e10 = __shfl_xor(a10, 8);
                    float e11 = __shfl_xor(a11, 8);
                    float gi, gf, gg, go;
                    if (mfS == 0) { gi = a00; gf = e00; gg = a01; go = e01; }
                    else          { gi = e10; gf = a10; gg = e11; go = a11; }
                    gi += b1v[0]; gf += b1v[1]; gg += b1v[2]; go += b1v[3];
                    int bb = row0 + mfS * 16 + kg * 4 + r;
                    float ii = sigm(gi), ff = sigm(gf), oo = sigm(go);
                    float tg = tanhf(gg);
                    float cn = ff * cv[r] + ii * tg;
                    cv[r] = cn;
                    float hn = oo * tanhf(cn);
                    stc2(&hb16[((size_t)(cell * 2 + parW) * B + bb) * H + jj], f2b(hn));
                }
            }
            if (p < NPH - 1) boundary(sc, p);
        }
    } else {
        // ================= logits =================
        const int b = (bid - 192) * 8 + wave;
        const int c = lane & 31, kh = lane >> 5;
        const int half = lane >> 5, qq = lane & 31;
        const int sww = (c & 7) << 4;
        const int rowbase = c * 2048;
        const int lenb = lens[b];
        const float bo = (c < NC) ? bout[c] : 0.f;
        char* scr = smem + 57344 + wave * 2048;

        for (int p = 0; p < NPH; ++p) {
            if (p >= 2) {
                const int t2 = p - 2, parL = p & 1;
                {
                    const ushort_t* src = hbloc + (size_t)((2 + half) * 2 + parL) * BHs
                                        + (size_t)b * H + qq * 16;
                    bf16x8 v0 = ldg8(src);
                    bf16x8 v1 = ldg8(src + 8);
                    char* dst = scr + half * 1024 + qq * 32;
                    *(bf16x8*)dst = v0;
                    *(bf16x8*)(dst + 16) = v1;
                }
                __syncthreads();
                float sum = 0.f;
                if (c < NC) {
                    const char* ybase = scr + kh * 1024;
                    #pragma unroll 8
                    for (int t = 0; t < 64; ++t) {
                        bf16x8 v = *(const bf16x8*)(ybase + t * 16);
                        bf16x8 w = *(const bf16x8*)(smem + rowbase + ((kh * 1024 + t * 16) ^ sww));
                        #pragma unroll
                        for (int i = 0; i < 8; ++i) sum += (float)v[i] * (float)w[i];
                    }
                }
                sum += __shfl_xor(sum, 32);
                if (kh == 0 && c < NC) {
                    float val = (t2 < lenb) ? (sum + bo) : 0.f;
                    stc4f(&out[((size_t)b * T + t2) * NC + c], val);
                }
            }
            if (p < NPH - 1) boundary(sc, p);
        }
    }
}

// ---------------- launch ----------------

extern "C" void kernel_launch(void* const* d_in, const int* in_sizes, int n_in,
                              void* d_out, int out_size, void* d_ws, size_t ws_size,
                              hipStream_t stream) {
    const int*   tok   = (const int*)d_in[0];
    const int*   lens  = (const int*)d_in[1];
    const float* h0    = (const float*)d_in[2];
    const float* c0    = (const float*)d_in[3];
    const float* embed = (const float*)d_in[4];
    const float* Wih0  = (const float*)d_in[5];
    const float* Wih1  = (const float*)d_in[6];
    const float* Whh   = (const float*)d_in[7];
    const float* bih   = (const float*)d_in[8];
    const float* bhh   = (const float*)d_in[9];
    const float* Wout  = (const float*)d_in[10];
    const float* bout  = (const float*)d_in[11];
    float* out = (float*)d_out;

    // workspace layout (~19.3 MB, < 20.55 MB proven in r1)
    ushort_t* hb16  = (ushort_t*)d_ws;                      // [4][2][B][H] bf16, 2MB
    ushort_t* hmir  = hb16 + (size_t)4 * 2 * B * H;         // [8 xcd][4][2][B][H] bf16, 16MB
    float*    G0    = (float*)(hmir + (size_t)8 * 4 * 2 * B * H);  // [2][28][512][4] f32
    float*    bias1 = G0 + 2 * NE * FH;                     // [2][2048] f32
    int*      cnt   = (int*)(bias1 + 2 * FH);               // CNT_TOTAL ints
    int*      tokT  = cnt + CNT_TOTAL;                      // [T][B] int

    (void)hipFuncSetAttribute((const void*)k_persist,
                              hipFuncAttributeMaxDynamicSharedMemorySize, LDS_BYTES);

    k_init<<<64, 256, 0, stream>>>(cnt);
    k_g0<<<(2 * NE * FH + 255) / 256, 256, 0, stream>>>(embed, Wih0, bih, bhh, G0, bias1);
    k_state<<<(4 * B * H + 255) / 256, 256, 0, stream>>>(h0, hb16);
    k_tokT<<<(B * T + 255) / 256, 256, 0, stream>>>(tok, tokT);
    k_len<<<1, 256, 0, stream>>>(lens, out + (size_t)B * T * NC);

    k_persist<<<NBLK, 512, LDS_BYTES, stream>>>(Whh, Wih1, G0, bias1, c0, hb16, hmir,
                                                tokT, lens, Wout, bout, out, cnt);
}

// Round 8
// 17644.182 us; speedup vs baseline: 1.5681x; 1.5681x over previous
//
#include <hip/hip_runtime.h>
#include <hip/hip_bf16.h>
#include <stdint.h>

typedef unsigned short ushort_t;
typedef unsigned long long u64_t;

#define H   512
#define E   128
#define NC  27
#define NE  28
#define B   256
#define T   512
#define FH  2048        // 4*H
#define NPH (T + 2)     // phases 0..T+1
#define NBLK 224        // 64 L0 + 128 L1 + 32 OUT
#define NCELL 16
#define BHs (B * H)
#define AOFF 32768      // A double-buffer: [0,32K) ; weights above
#define LDS_BYTES (128 * 1024)

typedef __bf16 bf16x8 __attribute__((ext_vector_type(8)));
typedef float  f32x4  __attribute__((ext_vector_type(4)));

__device__ __forceinline__ ushort_t f2b(float x) {
    uint32_t u = __float_as_uint(x);
    uint32_t r = (u + 0x7FFFu + ((u >> 16) & 1u)) >> 16;
    return (ushort_t)r;
}
__device__ __forceinline__ float sigm(float x) {
    return 1.f / (1.f + __expf(-x));
}
// write-through agent store — LLC-visible, no dirty L2 line
__device__ __forceinline__ void stc2(ushort_t* p, ushort_t v) {
    __hip_atomic_store(p, v, __ATOMIC_RELAXED, __HIP_MEMORY_SCOPE_AGENT);
}
__device__ __forceinline__ void stc4f(float* p, float v) {
    __hip_atomic_store(p, v, __ATOMIC_RELAXED, __HIP_MEMORY_SCOPE_AGENT);
}
__device__ __forceinline__ void gload_lds16(const void* g, void* l) {
    __builtin_amdgcn_global_load_lds(
        (const __attribute__((address_space(1))) void*)g,
        (__attribute__((address_space(3))) void*)l, 16, 0, 0);
}

// stage one A-chunk [256 rows][32 cols] (wave-private rows [32w,32w+32))
// LDS layout: row-major, 64B/row; content block-swizzled b ^= (row>>1)&3
// (applied on the GLOBAL source; LDS dest stays linear: lane*16).
__device__ __forceinline__ void stageA(const ushort_t* __restrict__ hsrc, int k0,
                                       char* ldsChunk, int wave, int lane) {
    int rbase = wave * 32 + (lane >> 2);
    int b = lane & 3;
    char* l0 = ldsChunk + wave * 2048;
    #pragma unroll
    for (int i = 0; i < 2; ++i) {
        int row = rbase + i * 16;
        int bs = b ^ ((row >> 1) & 3);
        const ushort_t* g = hsrc + (size_t)row * H + k0 + bs * 8;
        gload_lds16((const void*)g, (void*)(l0 + i * 1024));
    }
}

// ---------------- setup kernels ----------------

__global__ void k_init(int* __restrict__ cnt) {
    int i = blockIdx.x * blockDim.x + threadIdx.x;
    if (i < NPH * NCELL) cnt[i] = 0;
}

// G0 layout: [cell][token][j][gate] f32
__global__ void k_g0(const float* __restrict__ embed, const float* __restrict__ Wih0,
                     const float* __restrict__ bih, const float* __restrict__ bhh,
                     float* __restrict__ G0, float* __restrict__ bias1) {
    int i = blockIdx.x * blockDim.x + threadIdx.x;
    if (i < 2 * NE * FH) {
        int d = i / (NE * FH);
        int rem = i % (NE * FH);
        int e = rem / FH;
        int n = rem % FH;
        int g = n >> 9, j = n & 511;
        const float* er = embed + (size_t)e * E;
        const float* wr = Wih0 + ((size_t)d * FH + n) * E;
        float s = 0.f;
        #pragma unroll 8
        for (int k = 0; k < E; ++k) s += er[k] * wr[k];
        G0[(((size_t)d * NE + e) * 512 + j) * 4 + g]
            = s + bih[(size_t)d * FH + n] + bhh[(size_t)d * FH + n];
    }
    if (i < 2 * FH) bias1[i] = bih[2 * FH + i] + bhh[2 * FH + i];
}

__global__ void k_state(const float* __restrict__ h0, ushort_t* __restrict__ hb16) {
    int i = blockIdx.x * blockDim.x + threadIdx.x;
    if (i >= 4 * B * H) return;
    int cell = i / (B * H);
    int rem  = i % (B * H);
    hb16[((size_t)(cell * 2 + 1)) * (B * H) + rem] = f2b(h0[i]);   // parity 1 = step -1
}

__global__ void k_tokT(const int* __restrict__ tok, int* __restrict__ tokT) {
    int i = blockIdx.x * blockDim.x + threadIdx.x;
    if (i < B * T) {
        int b = i / T, t = i % T;
        tokT[(size_t)t * B + b] = tok[i];
    }
}

__global__ void k_len(const int* __restrict__ lens, float* __restrict__ out_len) {
    int i = threadIdx.x;
    if (i < B) out_len[i] = (float)lens[i];
}

// ---------------- grid barrier (relaxed poll + one acquire fence) ----------------
__device__ __forceinline__ void gbar(int* cnt, int p) {
    __syncthreads();        // drains all vmem incl. agent h-stores
    if (threadIdx.x == 0) {
        int* base = cnt + p * NCELL;
        __hip_atomic_fetch_add(base + (blockIdx.x & (NCELL - 1)), 1,
                               __ATOMIC_RELAXED, __HIP_MEMORY_SCOPE_AGENT);
        int total;
        do {
            total = 0;
            #pragma unroll
            for (int c2 = 0; c2 < NCELL; ++c2)
                total += __hip_atomic_load(base + c2, __ATOMIC_RELAXED, __HIP_MEMORY_SCOPE_AGENT);
            if (total < NBLK) __builtin_amdgcn_s_sleep(2);
        } while (total < NBLK);
    }
    __syncthreads();
    __builtin_amdgcn_fence(__ATOMIC_ACQUIRE, "agent");   // invalidate stale L1/L2 once
    __builtin_amdgcn_sched_barrier(0);
}

// Phase p: L0 step t=p (p<T); L1 step s=p-1 (1<=p<=T); OUT logits t2=p-2 (p>=2).
// hb16: [cell][parity][B][H] bf16, parity(step)=step&1.
__global__ __launch_bounds__(512, 2) void k_persist(
    const float* __restrict__ Whh, const float* __restrict__ Wih1,
    const float* __restrict__ G0, const float* __restrict__ bias1,
    const float* __restrict__ c0, ushort_t* __restrict__ hb16,
    const int* __restrict__ tokT, const int* __restrict__ lens,
    const float* __restrict__ Wout, const float* __restrict__ bout,
    float* __restrict__ out, int* __restrict__ cnt)
{
    extern __shared__ char smem[];
    const int bid = blockIdx.x;
    const int tid = threadIdx.x;
    const int lane = tid & 63, wave = tid >> 6;
    const int lrow = lane & 15, kg = lane >> 4;
    const int row0 = wave * 32;
    const int sw16 = (lrow & 7) << 4;
    // A-tile read addressing (bank-balanced via source swizzle)
    const int sA    = ((row0 + lrow) >> 1) & 3;
    const int aoff0 = (row0 + lrow) * 64 + ((kg ^ sA) << 4);
    const int aoff1 = aoff0 + 16 * 64;      // row+16: same swizzle class

    // ---- one-time: stage weights into LDS (f32 -> bf16, XOR-swizzled) ----
    if (bid < 64) {
        const int cell = bid >> 5, jt = bid & 31, j0 = jt * 16;
        const float* Wsrc = Whh + (size_t)cell * FH * H;
        for (int r = wave; r < 64; r += 8) {
            int grow = (r >> 4) * 512 + j0 + (r & 15);
            const float* src = Wsrc + (size_t)grow * H;
            int sw = (r & 7) << 4;
            for (int c = lane; c < H; c += 64) {
                int byte = AOFF + (((r * H + c) * 2) ^ sw);
                *(ushort_t*)(smem + byte) = f2b(src[c]);
            }
        }
    } else if (bid < 192) {
        const int q = bid - 64, cell = 2 + (q >> 6), jt = q & 63, j0 = jt * 8;
        const float* Wi = Wih1 + (size_t)(cell - 2) * FH * (2 * H);
        const float* Wh = Whh + (size_t)cell * FH * H;
        for (int r = wave; r < 32; r += 8) {
            int grow = (r >> 3) * 512 + j0 + (r & 7);
            const float* si = Wi + (size_t)grow * (2 * H);
            const float* sh = Wh + (size_t)grow * H;
            int sw = (r & 7) << 4;
            for (int c = lane; c < 1536; c += 64) {
                float v = (c < 1024) ? si[c] : sh[c - 1024];
                int byte = AOFF + (((r * 1536 + c) * 2) ^ sw);
                *(ushort_t*)(smem + byte) = f2b(v);
            }
        }
    } else {
        for (int r = wave; r < NC; r += 8) {
            const float* src = Wout + (size_t)r * (2 * H);
            int sw = (r & 7) << 4;
            for (int c = lane; c < 2 * H; c += 64) {
                int byte = ((r * (2 * H) + c) * 2) ^ sw;
                *(ushort_t*)(smem + byte) = f2b(src[c]);
            }
        }
    }
    __syncthreads();

    if (bid < 64) {
        // ================= layer 0 =================
        const int cell = bid >> 5, jt = bid & 31, j0 = jt * 16;
        const int j = j0 + lrow;

        float cv[8];
        #pragma unroll
        for (int i = 0; i < 8; ++i) {
            int bb = row0 + (i >> 2) * 16 + kg * 4 + (i & 3);
            cv[i] = c0[((size_t)cell * B + bb) * H + j];
        }
        // prime G0 gather for p=0
        f32x4 g0v[8];
        #pragma unroll
        for (int i = 0; i < 8; ++i) {
            int bb = row0 + (i >> 2) * 16 + kg * 4 + (i & 3);
            int tk = tokT[bb];
            g0v[i] = *(const f32x4*)(G0 + (((size_t)cell * NE + tk) * 512 + j) * 4);
        }

        for (int p = 0; p < NPH; ++p) {
            if (p < T) {
                const int parR = (p + 1) & 1, parW = p & 1;
                const ushort_t* hsrc = hb16 + (size_t)(cell * 2 + parR) * BHs;

                // prologue: stage chunks 0,1
                stageA(hsrc, 0,  smem,         wave, lane);
                stageA(hsrc, 32, smem + 16384, wave, lane);

                f32x4 acc[2][4];
                #pragma unroll
                for (int m = 0; m < 2; ++m)
                    #pragma unroll
                    for (int g = 0; g < 4; ++g) acc[m][g] = (f32x4){0.f, 0.f, 0.f, 0.f};

                #pragma unroll
                for (int t = 0; t < 16; ++t) {
                    if (t < 15) asm volatile("s_waitcnt vmcnt(2)" ::: "memory");
                    else        asm volatile("s_waitcnt vmcnt(0)" ::: "memory");
                    __builtin_amdgcn_sched_barrier(0);
                    const char* Ab = smem + (t & 1) * 16384;
                    bf16x8 a0 = *(const bf16x8*)(Ab + aoff0);
                    bf16x8 a1 = *(const bf16x8*)(Ab + aoff1);
                    int cb = (kg * 16 + t * 64) ^ sw16;
                    bf16x8 w0 = *(const bf16x8*)(smem + AOFF + (0 * 16 + lrow) * 1024 + cb);
                    bf16x8 w1 = *(const bf16x8*)(smem + AOFF + (1 * 16 + lrow) * 1024 + cb);
                    bf16x8 w2 = *(const bf16x8*)(smem + AOFF + (2 * 16 + lrow) * 1024 + cb);
                    bf16x8 w3 = *(const bf16x8*)(smem + AOFF + (3 * 16 + lrow) * 1024 + cb);
                    asm volatile("s_waitcnt lgkmcnt(0)" ::: "memory");
                    __builtin_amdgcn_sched_barrier(0);
                    if (t < 14) stageA(hsrc, (t + 2) * 32, smem + (t & 1) * 16384, wave, lane);
                    __builtin_amdgcn_sched_barrier(0);
                    acc[0][0] = __builtin_amdgcn_mfma_f32_16x16x32_bf16(a0, w0, acc[0][0], 0, 0, 0);
                    acc[1][0] = __builtin_amdgcn_mfma_f32_16x16x32_bf16(a1, w0, acc[1][0], 0, 0, 0);
                    acc[0][1] = __builtin_amdgcn_mfma_f32_16x16x32_bf16(a0, w1, acc[0][1], 0, 0, 0);
                    acc[1][1] = __builtin_amdgcn_mfma_f32_16x16x32_bf16(a1, w1, acc[1][1], 0, 0, 0);
                    acc[0][2] = __builtin_amdgcn_mfma_f32_16x16x32_bf16(a0, w2, acc[0][2], 0, 0, 0);
                    acc[1][2] = __builtin_amdgcn_mfma_f32_16x16x32_bf16(a1, w2, acc[1][2], 0, 0, 0);
                    acc[0][3] = __builtin_amdgcn_mfma_f32_16x16x32_bf16(a0, w3, acc[0][3], 0, 0, 0);
                    acc[1][3] = __builtin_amdgcn_mfma_f32_16x16x32_bf16(a1, w3, acc[1][3], 0, 0, 0);
                }

                #pragma unroll
                for (int i = 0; i < 8; ++i) {
                    int mf = i >> 2, r = i & 3;
                    int bb = row0 + mf * 16 + kg * 4 + r;
                    float gi = acc[mf][0][r] + g0v[i][0];
                    float gf = acc[mf][1][r] + g0v[i][1];
                    float gg = acc[mf][2][r] + g0v[i][2];
                    float go = acc[mf][3][r] + g0v[i][3];
                    float ii = sigm(gi), ff = sigm(gf), oo = sigm(go);
                    float tg = tanhf(gg);
                    float cn = ff * cv[i] + ii * tg;
                    cv[i] = cn;
                    float hn = oo * tanhf(cn);
                    stc2(&hb16[((size_t)(cell * 2 + parW) * B + bb) * H + j], f2b(hn));
                }
                // prefetch next step's tok/G0 (immutable data; hides under barrier)
                if (p + 1 < T) {
                    #pragma unroll
                    for (int i = 0; i < 8; ++i) {
                        int bb = row0 + (i >> 2) * 16 + kg * 4 + (i & 3);
                        int tk = tokT[(size_t)(p + 1) * B + bb];
                        g0v[i] = *(const f32x4*)(G0 + (((size_t)cell * NE + tk) * 512 + j) * 4);
                    }
                }
            }
            if (p < NPH - 1) gbar(cnt, p);
        }
    } else if (bid < 192) {
        // ================= layer 1 =================
        const int q = bid - 64, cell = 2 + (q >> 6), jt = q & 63, j0 = jt * 8;
        const int cc = lrow;
        const int jj = j0 + (cc & 7);
        const int mfS = cc >> 3;

        float b1v[4];
        #pragma unroll
        for (int g = 0; g < 4; ++g) b1v[g] = bias1[(size_t)(cell - 2) * FH + g * 512 + jj];

        float cv[4];
        #pragma unroll
        for (int r = 0; r < 4; ++r) {
            int bb = row0 + mfS * 16 + kg * 4 + r;
            cv[r] = c0[((size_t)cell * B + bb) * H + jj];
        }

        for (int p = 0; p < NPH; ++p) {
            if (p >= 1 && p <= T) {
                const int parY  = (p + 1) & 1;
                const int parR2 = p & 1;
                const int parW  = (p + 1) & 1;
                const ushort_t* base0 = hb16 + (size_t)(0 * 2 + parY) * BHs;
                const ushort_t* base1 = hb16 + (size_t)(2 + parY) * BHs;
                const ushort_t* base2 = hb16 + (size_t)(cell * 2 + parR2) * BHs;

                stageA(base0, 0,  smem,         wave, lane);
                stageA(base0, 32, smem + 16384, wave, lane);

                f32x4 acc[2][2];
                #pragma unroll
                for (int m = 0; m < 2; ++m)
                    #pragma unroll
                    for (int n = 0; n < 2; ++n) acc[m][n] = (f32x4){0.f, 0.f, 0.f, 0.f};

                #pragma unroll
                for (int t = 0; t < 48; ++t) {
                    if (t < 47) asm volatile("s_waitcnt vmcnt(2)" ::: "memory");
                    else        asm volatile("s_waitcnt vmcnt(0)" ::: "memory");
                    __builtin_amdgcn_sched_barrier(0);
                    const char* Ab = smem + (t & 1) * 16384;
                    bf16x8 a0 = *(const bf16x8*)(Ab + aoff0);
                    bf16x8 a1 = *(const bf16x8*)(Ab + aoff1);
                    int cb = (t * 64 + kg * 16) ^ sw16;
                    bf16x8 b0 = *(const bf16x8*)(smem + AOFF + lrow * 3072 + cb);
                    bf16x8 b1 = *(const bf16x8*)(smem + AOFF + (16 + lrow) * 3072 + cb);
                    asm volatile("s_waitcnt lgkmcnt(0)" ::: "memory");
                    __builtin_amdgcn_sched_barrier(0);
                    if (t < 46) {
                        int c2 = t + 2;
                        const ushort_t* src = (c2 < 16) ? base0 : (c2 < 32) ? base1 : base2;
                        stageA(src, (c2 & 15) * 32, smem + (t & 1) * 16384, wave, lane);
                    }
                    __builtin_amdgcn_sched_barrier(0);
                    acc[0][0] = __builtin_amdgcn_mfma_f32_16x16x32_bf16(a0, b0, acc[0][0], 0, 0, 0);
                    acc[0][1] = __builtin_amdgcn_mfma_f32_16x16x32_bf16(a0, b1, acc[0][1], 0, 0, 0);
                    acc[1][0] = __builtin_amdgcn_mfma_f32_16x16x32_bf16(a1, b0, acc[1][0], 0, 0, 0);
                    acc[1][1] = __builtin_amdgcn_mfma_f32_16x16x32_bf16(a1, b1, acc[1][1], 0, 0, 0);
                }

                #pragma unroll
                for (int r = 0; r < 4; ++r) {
                    float a00 = acc[0][0][r], a01 = acc[0][1][r];
                    float a10 = acc[1][0][r], a11 = acc[1][1][r];
                    float e00 = __shfl_xor(a00, 8);
                    float e01 = __shfl_xor(a01, 8);
                    float e10 = __shfl_xor(a10, 8);
                    float e11 = __shfl_xor(a11, 8);
                    float gi, gf, gg, go;
                    if (mfS == 0) { gi = a00; gf = e00; gg = a01; go = e01; }
                    else          { gi = e10; gf = a10; gg = e11; go = a11; }
                    gi += b1v[0]; gf += b1v[1]; gg += b1v[2]; go += b1v[3];
                    int bb = row0 + mfS * 16 + kg * 4 + r;
                    float ii = sigm(gi), ff = sigm(gf), oo = sigm(go);
                    float tg = tanhf(gg);
                    float cn = ff * cv[r] + ii * tg;
                    cv[r] = cn;
                    float hn = oo * tanhf(cn);
                    stc2(&hb16[((size_t)(cell * 2 + parW) * B + bb) * H + jj], f2b(hn));
                }
            }
            if (p < NPH - 1) gbar(cnt, p);
        }
    } else {
        // ================= logits =================
        const int b = (bid - 192) * 8 + wave;
        const int c = lane & 31, kh = lane >> 5;
        const int half = lane >> 5, qq = lane & 31;
        const int sww = (c & 7) << 4;
        const int rowbase = c * 2048;
        const int lenb = lens[b];
        const float bo = (c < NC) ? bout[c] : 0.f;
        char* scr = smem + 57344 + wave * 2048;

        for (int p = 0; p < NPH; ++p) {
            if (p >= 2) {
                const int t2 = p - 2, parL = p & 1;
                {
                    const ushort_t* src = hb16 + (size_t)((2 + half) * 2 + parL) * BHs
                                        + (size_t)b * H + qq * 16;
                    bf16x8 v0 = *(const bf16x8*)src;
                    bf16x8 v1 = *(const bf16x8*)(src + 8);
                    char* dst = scr + half * 1024 + qq * 32;
                    *(bf16x8*)dst = v0;
                    *(bf16x8*)(dst + 16) = v1;
                }
                __syncthreads();
                float sum = 0.f;
                if (c < NC) {
                    const char* ybase = scr + kh * 1024;
                    #pragma unroll 8
                    for (int t = 0; t < 64; ++t) {
                        bf16x8 v = *(const bf16x8*)(ybase + t * 16);
                        bf16x8 w = *(const bf16x8*)(smem + rowbase + ((kh * 1024 + t * 16) ^ sww));
                        #pragma unroll
                        for (int i = 0; i < 8; ++i) sum += (float)v[i] * (float)w[i];
                    }
                }
                sum += __shfl_xor(sum, 32);
                if (kh == 0 && c < NC) {
                    float val = (t2 < lenb) ? (sum + bo) : 0.f;
                    stc4f(&out[((size_t)b * T + t2) * NC + c], val);
                }
            }
            if (p < NPH - 1) gbar(cnt, p);
        }
    }
}

// ---------------- launch ----------------

extern "C" void kernel_launch(void* const* d_in, const int* in_sizes, int n_in,
                              void* d_out, int out_size, void* d_ws, size_t ws_size,
                              hipStream_t stream) {
    const int*   tok   = (const int*)d_in[0];
    const int*   lens  = (const int*)d_in[1];
    const float* h0    = (const float*)d_in[2];
    const float* c0    = (const float*)d_in[3];
    const float* embed = (const float*)d_in[4];
    const float* Wih0  = (const float*)d_in[5];
    const float* Wih1  = (const float*)d_in[6];
    const float* Whh   = (const float*)d_in[7];
    const float* bih   = (const float*)d_in[8];
    const float* bhh   = (const float*)d_in[9];
    const float* Wout  = (const float*)d_in[10];
    const float* bout  = (const float*)d_in[11];
    float* out = (float*)d_out;

    ushort_t* hb16  = (ushort_t*)d_ws;                      // [4][2][B][H] bf16
    float*    G0    = (float*)(hb16 + (size_t)4 * 2 * B * H); // [2][28][512][4] f32
    float*    bias1 = G0 + 2 * NE * FH;                     // [2][2048] f32
    int*      cnt   = (int*)(bias1 + 2 * FH);               // [NPH][NCELL]
    int*      tokT  = cnt + NPH * NCELL;                    // [T][B]

    (void)hipFuncSetAttribute((const void*)k_persist,
                              hipFuncAttributeMaxDynamicSharedMemorySize, LDS_BYTES);

    k_init<<<(NPH * NCELL + 255) / 256, 256, 0, stream>>>(cnt);
    k_g0<<<(2 * NE * FH + 255) / 256, 256, 0, stream>>>(embed, Wih0, bih, bhh, G0, bias1);
    k_state<<<(4 * B * H + 255) / 256, 256, 0, stream>>>(h0, hb16);
    k_tokT<<<(B * T + 255) / 256, 256, 0, stream>>>(tok, tokT);
    k_len<<<1, 256, 0, stream>>>(lens, out + (size_t)B * T * NC);

    k_persist<<<NBLK, 512, LDS_BYTES, stream>>>(Whh, Wih1, G0, bias1, c0, hb16,
                                                tokT, lens, Wout, bout, out, cnt);
}

// Round 9
// 12907.294 us; speedup vs baseline: 2.1436x; 1.3670x over previous
//
#include <hip/hip_runtime.h>
#include <hip/hip_bf16.h>
#include <stdint.h>

typedef unsigned short ushort_t;
typedef unsigned long long u64_t;

#define H   512
#define E   128
#define NC  27
#define NE  28
#define B   256
#define T   512
#define FH  2048        // 4*H
#define NPH (T + 2)     // phases 0..T+1
#define NBLK 224        // 64 L0 + 128 L1 + 32 OUT
#define NCELL 16
#define BHs (B * H)
#define AOFF 65536      // A 4-deep double-buffer in [0,64K); weights above
#define LDS_BYTES (160 * 1024)

typedef __bf16 bf16x8 __attribute__((ext_vector_type(8)));
typedef float  f32x4  __attribute__((ext_vector_type(4)));

#define WAITV(n) asm volatile("s_waitcnt vmcnt(" #n ")" ::: "memory")

__device__ __forceinline__ ushort_t f2b(float x) {
    uint32_t u = __float_as_uint(x);
    uint32_t r = (u + 0x7FFFu + ((u >> 16) & 1u)) >> 16;
    return (ushort_t)r;
}
__device__ __forceinline__ float sigm(float x) {
    return 1.f / (1.f + __expf(-x));
}
// write-through agent store — LLC-visible, no dirty L2 line
__device__ __forceinline__ void stc2(ushort_t* p, ushort_t v) {
    __hip_atomic_store(p, v, __ATOMIC_RELAXED, __HIP_MEMORY_SCOPE_AGENT);
}
__device__ __forceinline__ void stc4f(float* p, float v) {
    __hip_atomic_store(p, v, __ATOMIC_RELAXED, __HIP_MEMORY_SCOPE_AGENT);
}
// LLC-coherent 16B load (bypasses L1/L2) — OUT-role staging
__device__ __forceinline__ bf16x8 ldc16(const ushort_t* p) {
    union { u64_t q[2]; bf16x8 v; } u;
    u.q[0] = __hip_atomic_load((const u64_t*)p,       __ATOMIC_RELAXED, __HIP_MEMORY_SCOPE_AGENT);
    u.q[1] = __hip_atomic_load(((const u64_t*)p) + 1, __ATOMIC_RELAXED, __HIP_MEMORY_SCOPE_AGENT);
    return u.v;
}
// async global->LDS, 16B/lane, CPol sc0|sc1 (=17): LLC-coherent, no L2 allocate
__device__ __forceinline__ void gload_lds16c(const void* g, void* l) {
    __builtin_amdgcn_global_load_lds(
        (const __attribute__((address_space(1))) void*)g,
        (__attribute__((address_space(3))) void*)l, 16, 0, 17);
}

// stage one A-chunk [256 rows][32 cols] (wave-private rows [32w,32w+32))
// LDS: linear dest (row-major 64B/row); content swizzled b ^= (row>>1)&3
// applied on the GLOBAL source (G21: linear dest + inverse-swz source).
__device__ __forceinline__ void stageA(const ushort_t* __restrict__ hsrc, int k0,
                                       char* ldsChunk, int wave, int lane) {
    int rbase = wave * 32 + (lane >> 2);
    int b = lane & 3;
    char* l0 = ldsChunk + wave * 2048;
    #pragma unroll
    for (int i = 0; i < 2; ++i) {
        int row = rbase + i * 16;
        int bs = b ^ ((row >> 1) & 3);
        const ushort_t* g = hsrc + (size_t)row * H + k0 + bs * 8;
        gload_lds16c((const void*)g, (void*)(l0 + i * 1024));
    }
}

// ---------------- setup kernels ----------------

__global__ void k_init(int* __restrict__ cnt) {
    int i = blockIdx.x * blockDim.x + threadIdx.x;
    if (i < NPH * NCELL) cnt[i] = 0;
}

// G0 layout: [cell][token][j][gate] f32
__global__ void k_g0(const float* __restrict__ embed, const float* __restrict__ Wih0,
                     const float* __restrict__ bih, const float* __restrict__ bhh,
                     float* __restrict__ G0, float* __restrict__ bias1) {
    int i = blockIdx.x * blockDim.x + threadIdx.x;
    if (i < 2 * NE * FH) {
        int d = i / (NE * FH);
        int rem = i % (NE * FH);
        int e = rem / FH;
        int n = rem % FH;
        int g = n >> 9, j = n & 511;
        const float* er = embed + (size_t)e * E;
        const float* wr = Wih0 + ((size_t)d * FH + n) * E;
        float s = 0.f;
        #pragma unroll 8
        for (int k = 0; k < E; ++k) s += er[k] * wr[k];
        G0[(((size_t)d * NE + e) * 512 + j) * 4 + g]
            = s + bih[(size_t)d * FH + n] + bhh[(size_t)d * FH + n];
    }
    if (i < 2 * FH) bias1[i] = bih[2 * FH + i] + bhh[2 * FH + i];
}

__global__ void k_state(const float* __restrict__ h0, ushort_t* __restrict__ hb16) {
    int i = blockIdx.x * blockDim.x + threadIdx.x;
    if (i >= 4 * B * H) return;
    int cell = i / (B * H);
    int rem  = i % (B * H);
    hb16[((size_t)(cell * 2 + 1)) * (B * H) + rem] = f2b(h0[i]);   // parity 1 = step -1
}

__global__ void k_tokT(const int* __restrict__ tok, int* __restrict__ tokT) {
    int i = blockIdx.x * blockDim.x + threadIdx.x;
    if (i < B * T) {
        int b = i / T, t = i % T;
        tokT[(size_t)t * B + b] = tok[i];
    }
}

__global__ void k_len(const int* __restrict__ lens, float* __restrict__ out_len) {
    int i = threadIdx.x;
    if (i < B) out_len[i] = (float)lens[i];
}

// ---------------- grid barrier (fence-free, r4-proven) ----------------
__device__ __forceinline__ void gbar(int* cnt, int p) {
    __syncthreads();        // drains all vmem incl. agent h-stores
    if (threadIdx.x == 0) {
        int* base = cnt + p * NCELL;
        __hip_atomic_fetch_add(base + (blockIdx.x & (NCELL - 1)), 1,
                               __ATOMIC_RELAXED, __HIP_MEMORY_SCOPE_AGENT);
        int total;
        do {
            total = 0;
            #pragma unroll
            for (int c2 = 0; c2 < NCELL; ++c2)
                total += __hip_atomic_load(base + c2, __ATOMIC_RELAXED, __HIP_MEMORY_SCOPE_AGENT);
            if (total < NBLK) __builtin_amdgcn_s_sleep(2);
        } while (total < NBLK);
    }
    __syncthreads();
    __builtin_amdgcn_sched_barrier(0);
}

// Phase p: L0 step t=p (p<T); L1 step s=p-1 (1<=p<=T); OUT logits t2=p-2 (p>=2).
// hb16: [cell][parity][B][H] bf16, parity(step)=step&1.
__global__ __launch_bounds__(512, 2) void k_persist(
    const float* __restrict__ Whh, const float* __restrict__ Wih1,
    const float* __restrict__ G0, const float* __restrict__ bias1,
    const float* __restrict__ c0, ushort_t* __restrict__ hb16,
    const int* __restrict__ tokT, const int* __restrict__ lens,
    const float* __restrict__ Wout, const float* __restrict__ bout,
    float* __restrict__ out, int* __restrict__ cnt)
{
    extern __shared__ char smem[];
    const int bid = blockIdx.x;
    const int tid = threadIdx.x;
    const int lane = tid & 63, wave = tid >> 6;
    const int lrow = lane & 15, kg = lane >> 4;
    const int row0 = wave * 32;
    const int sw16 = (lrow & 7) << 4;
    // A-tile read addressing (matches stageA's source swizzle)
    const int sA    = ((row0 + lrow) >> 1) & 3;
    const int aoff0 = (row0 + lrow) * 64 + ((kg ^ sA) << 4);
    const int aoff1 = aoff0 + 16 * 64;      // row+16: same swizzle class

    // ---- one-time: stage weights into LDS (f32 -> bf16, XOR-swizzled) ----
    if (bid < 64) {
        const int cell = bid >> 5, jt = bid & 31, j0 = jt * 16;
        const float* Wsrc = Whh + (size_t)cell * FH * H;
        for (int r = wave; r < 64; r += 8) {
            int grow = (r >> 4) * 512 + j0 + (r & 15);
            const float* src = Wsrc + (size_t)grow * H;
            int sw = (r & 7) << 4;
            for (int c = lane; c < H; c += 64) {
                int byte = AOFF + (((r * H + c) * 2) ^ sw);
                *(ushort_t*)(smem + byte) = f2b(src[c]);
            }
        }
    } else if (bid < 192) {
        const int q = bid - 64, cell = 2 + (q >> 6), jt = q & 63, j0 = jt * 8;
        const float* Wi = Wih1 + (size_t)(cell - 2) * FH * (2 * H);
        const float* Wh = Whh + (size_t)cell * FH * H;
        for (int r = wave; r < 32; r += 8) {
            int grow = (r >> 3) * 512 + j0 + (r & 7);
            const float* si = Wi + (size_t)grow * (2 * H);
            const float* sh = Wh + (size_t)grow * H;
            int sw = (r & 7) << 4;
            for (int c = lane; c < 1536; c += 64) {
                float v = (c < 1024) ? si[c] : sh[c - 1024];
                int byte = AOFF + (((r * 1536 + c) * 2) ^ sw);
                *(ushort_t*)(smem + byte) = f2b(v);
            }
        }
    } else {
        for (int r = wave; r < NC; r += 8) {
            const float* src = Wout + (size_t)r * (2 * H);
            int sw = (r & 7) << 4;
            for (int c = lane; c < 2 * H; c += 64) {
                int byte = ((r * (2 * H) + c) * 2) ^ sw;
                *(ushort_t*)(smem + byte) = f2b(src[c]);
            }
        }
    }
    __syncthreads();

    if (bid < 64) {
        // ================= layer 0 =================
        const int cell = bid >> 5, jt = bid & 31, j0 = jt * 16;
        const int j = j0 + lrow;

        float cv[8];
        #pragma unroll
        for (int i = 0; i < 8; ++i) {
            int bb = row0 + (i >> 2) * 16 + kg * 4 + (i & 3);
            cv[i] = c0[((size_t)cell * B + bb) * H + j];
        }
        // prime G0 gather for p=0
        f32x4 g0v[8];
        #pragma unroll
        for (int i = 0; i < 8; ++i) {
            int bb = row0 + (i >> 2) * 16 + kg * 4 + (i & 3);
            int tk = tokT[bb];
            g0v[i] = *(const f32x4*)(G0 + (((size_t)cell * NE + tk) * 512 + j) * 4);
        }

        for (int p = 0; p < NPH; ++p) {
            if (p < T) {
                const int parR = (p + 1) & 1, parW = p & 1;
                const ushort_t* hsrc = hb16 + (size_t)(cell * 2 + parR) * BHs;

                // prologue: stage chunks 0..3
                #pragma unroll
                for (int c2 = 0; c2 < 4; ++c2)
                    stageA(hsrc, c2 * 32, smem + c2 * 16384, wave, lane);

                f32x4 acc[2][4];
                #pragma unroll
                for (int m = 0; m < 2; ++m)
                    #pragma unroll
                    for (int g = 0; g < 4; ++g) acc[m][g] = (f32x4){0.f, 0.f, 0.f, 0.f};

                #pragma unroll
                for (int t = 0; t < 16; ++t) {
                    const int rem = 15 - t;
                    if (rem >= 3)      WAITV(6);
                    else if (rem == 2) WAITV(4);
                    else if (rem == 1) WAITV(2);
                    else               WAITV(0);
                    __builtin_amdgcn_sched_barrier(0);
                    const char* Ab = smem + (t & 3) * 16384;
                    bf16x8 a0 = *(const bf16x8*)(Ab + aoff0);
                    bf16x8 a1 = *(const bf16x8*)(Ab + aoff1);
                    int cb = (kg * 16 + t * 64) ^ sw16;
                    bf16x8 w0 = *(const bf16x8*)(smem + AOFF + (0 * 16 + lrow) * 1024 + cb);
                    bf16x8 w1 = *(const bf16x8*)(smem + AOFF + (1 * 16 + lrow) * 1024 + cb);
                    bf16x8 w2 = *(const bf16x8*)(smem + AOFF + (2 * 16 + lrow) * 1024 + cb);
                    bf16x8 w3 = *(const bf16x8*)(smem + AOFF + (3 * 16 + lrow) * 1024 + cb);
                    asm volatile("s_waitcnt lgkmcnt(0)" ::: "memory");
                    __builtin_amdgcn_sched_barrier(0);
                    if (t + 4 < 16) stageA(hsrc, (t + 4) * 32, smem + (t & 3) * 16384, wave, lane);
                    __builtin_amdgcn_sched_barrier(0);
                    acc[0][0] = __builtin_amdgcn_mfma_f32_16x16x32_bf16(a0, w0, acc[0][0], 0, 0, 0);
                    acc[1][0] = __builtin_amdgcn_mfma_f32_16x16x32_bf16(a1, w0, acc[1][0], 0, 0, 0);
                    acc[0][1] = __builtin_amdgcn_mfma_f32_16x16x32_bf16(a0, w1, acc[0][1], 0, 0, 0);
                    acc[1][1] = __builtin_amdgcn_mfma_f32_16x16x32_bf16(a1, w1, acc[1][1], 0, 0, 0);
                    acc[0][2] = __builtin_amdgcn_mfma_f32_16x16x32_bf16(a0, w2, acc[0][2], 0, 0, 0);
                    acc[1][2] = __builtin_amdgcn_mfma_f32_16x16x32_bf16(a1, w2, acc[1][2], 0, 0, 0);
                    acc[0][3] = __builtin_amdgcn_mfma_f32_16x16x32_bf16(a0, w3, acc[0][3], 0, 0, 0);
                    acc[1][3] = __builtin_amdgcn_mfma_f32_16x16x32_bf16(a1, w3, acc[1][3], 0, 0, 0);
                }

                #pragma unroll
                for (int i = 0; i < 8; ++i) {
                    int mf = i >> 2, r = i & 3;
                    int bb = row0 + mf * 16 + kg * 4 + r;
                    float gi = acc[mf][0][r] + g0v[i][0];
                    float gf = acc[mf][1][r] + g0v[i][1];
                    float gg = acc[mf][2][r] + g0v[i][2];
                    float go = acc[mf][3][r] + g0v[i][3];
                    float ii = sigm(gi), ff = sigm(gf), oo = sigm(go);
                    float tg = tanhf(gg);
                    float cn = ff * cv[i] + ii * tg;
                    cv[i] = cn;
                    float hn = oo * tanhf(cn);
                    stc2(&hb16[((size_t)(cell * 2 + parW) * B + bb) * H + j], f2b(hn));
                }
                // prefetch next step's tok/G0 (immutable; now L2-resident)
                if (p + 1 < T) {
                    #pragma unroll
                    for (int i = 0; i < 8; ++i) {
                        int bb = row0 + (i >> 2) * 16 + kg * 4 + (i & 3);
                        int tk = tokT[(size_t)(p + 1) * B + bb];
                        g0v[i] = *(const f32x4*)(G0 + (((size_t)cell * NE + tk) * 512 + j) * 4);
                    }
                }
            }
            if (p < NPH - 1) gbar(cnt, p);
        }
    } else if (bid < 192) {
        // ================= layer 1 =================
        const int q = bid - 64, cell = 2 + (q >> 6), jt = q & 63, j0 = jt * 8;
        const int cc = lrow;
        const int jj = j0 + (cc & 7);
        const int mfS = cc >> 3;

        float b1v[4];
        #pragma unroll
        for (int g = 0; g < 4; ++g) b1v[g] = bias1[(size_t)(cell - 2) * FH + g * 512 + jj];

        float cv[4];
        #pragma unroll
        for (int r = 0; r < 4; ++r) {
            int bb = row0 + mfS * 16 + kg * 4 + r;
            cv[r] = c0[((size_t)cell * B + bb) * H + jj];
        }

        for (int p = 0; p < NPH; ++p) {
            if (p >= 1 && p <= T) {
                const int parY  = (p + 1) & 1;
                const int parR2 = p & 1;
                const int parW  = (p + 1) & 1;
                const ushort_t* base0 = hb16 + (size_t)(0 * 2 + parY) * BHs;
                const ushort_t* base1 = hb16 + (size_t)(2 + parY) * BHs;
                const ushort_t* base2 = hb16 + (size_t)(cell * 2 + parR2) * BHs;

                #pragma unroll
                for (int c2 = 0; c2 < 4; ++c2)
                    stageA(base0, c2 * 32, smem + c2 * 16384, wave, lane);

                f32x4 acc[2][2];
                #pragma unroll
                for (int m = 0; m < 2; ++m)
                    #pragma unroll
                    for (int n = 0; n < 2; ++n) acc[m][n] = (f32x4){0.f, 0.f, 0.f, 0.f};

                #pragma unroll
                for (int t = 0; t < 48; ++t) {
                    const int rem = 47 - t;
                    if (rem >= 3)      WAITV(6);
                    else if (rem == 2) WAITV(4);
                    else if (rem == 1) WAITV(2);
                    else               WAITV(0);
                    __builtin_amdgcn_sched_barrier(0);
                    const char* Ab = smem + (t & 3) * 16384;
                    bf16x8 a0 = *(const bf16x8*)(Ab + aoff0);
                    bf16x8 a1 = *(const bf16x8*)(Ab + aoff1);
                    int cb = (t * 64 + kg * 16) ^ sw16;
                    bf16x8 b0 = *(const bf16x8*)(smem + AOFF + lrow * 3072 + cb);
                    bf16x8 b1 = *(const bf16x8*)(smem + AOFF + (16 + lrow) * 3072 + cb);
                    asm volatile("s_waitcnt lgkmcnt(0)" ::: "memory");
                    __builtin_amdgcn_sched_barrier(0);
                    if (t + 4 < 48) {
                        int c2 = t + 4;
                        const ushort_t* src = (c2 < 16) ? base0 : (c2 < 32) ? base1 : base2;
                        stageA(src, (c2 & 15) * 32, smem + (t & 3) * 16384, wave, lane);
                    }
                    __builtin_amdgcn_sched_barrier(0);
                    acc[0][0] = __builtin_amdgcn_mfma_f32_16x16x32_bf16(a0, b0, acc[0][0], 0, 0, 0);
                    acc[0][1] = __builtin_amdgcn_mfma_f32_16x16x32_bf16(a0, b1, acc[0][1], 0, 0, 0);
                    acc[1][0] = __builtin_amdgcn_mfma_f32_16x16x32_bf16(a1, b0, acc[1][0], 0, 0, 0);
                    acc[1][1] = __builtin_amdgcn_mfma_f32_16x16x32_bf16(a1, b1, acc[1][1], 0, 0, 0);
                }

                #pragma unroll
                for (int r = 0; r < 4; ++r) {
                    float a00 = acc[0][0][r], a01 = acc[0][1][r];
                    float a10 = acc[1][0][r], a11 = acc[1][1][r];
                    float e00 = __shfl_xor(a00, 8);
                    float e01 = __shfl_xor(a01, 8);
                    float e10 = __shfl_xor(a10, 8);
                    float e11 = __shfl_xor(a11, 8);
                    float gi, gf, gg, go;
                    if (mfS == 0) { gi = a00; gf = e00; gg = a01; go = e01; }
                    else          { gi = e10; gf = a10; gg = e11; go = a11; }
                    gi += b1v[0]; gf += b1v[1]; gg += b1v[2]; go += b1v[3];
                    int bb = row0 + mfS * 16 + kg * 4 + r;
                    float ii = sigm(gi), ff = sigm(gf), oo = sigm(go);
                    float tg = tanhf(gg);
                    float cn = ff * cv[r] + ii * tg;
                    cv[r] = cn;
                    float hn = oo * tanhf(cn);
                    stc2(&hb16[((size_t)(cell * 2 + parW) * B + bb) * H + jj], f2b(hn));
                }
            }
            if (p < NPH - 1) gbar(cnt, p);
        }
    } else {
        // ================= logits =================
        const int b = (bid - 192) * 8 + wave;
        const int c = lane & 31, kh = lane >> 5;
        const int half = lane >> 5, qq = lane & 31;
        const int sww = (c & 7) << 4;
        const int rowbase = c * 2048;
        const int lenb = lens[b];
        const float bo = (c < NC) ? bout[c] : 0.f;
        char* scr = smem + 57344 + wave * 2048;

        for (int p = 0; p < NPH; ++p) {
            if (p >= 2) {
                const int t2 = p - 2, parL = p & 1;
                {
                    const ushort_t* src = hb16 + (size_t)((2 + half) * 2 + parL) * BHs
                                        + (size_t)b * H + qq * 16;
                    bf16x8 v0 = ldc16(src);
                    bf16x8 v1 = ldc16(src + 8);
                    char* dst = scr + half * 1024 + qq * 32;
                    *(bf16x8*)dst = v0;
                    *(bf16x8*)(dst + 16) = v1;
                }
                __syncthreads();
                float sum = 0.f;
                if (c < NC) {
                    const char* ybase = scr + kh * 1024;
                    #pragma unroll 8
                    for (int t = 0; t < 64; ++t) {
                        bf16x8 v = *(const bf16x8*)(ybase + t * 16);
                        bf16x8 w = *(const bf16x8*)(smem + rowbase + ((kh * 1024 + t * 16) ^ sww));
                        #pragma unroll
                        for (int i = 0; i < 8; ++i) sum += (float)v[i] * (float)w[i];
                    }
                }
                sum += __shfl_xor(sum, 32);
                if (kh == 0 && c < NC) {
                    float val = (t2 < lenb) ? (sum + bo) : 0.f;
                    stc4f(&out[((size_t)b * T + t2) * NC + c], val);
                }
            }
            if (p < NPH - 1) gbar(cnt, p);
        }
    }
}

// ---------------- launch ----------------

extern "C" void kernel_launch(void* const* d_in, const int* in_sizes, int n_in,
                              void* d_out, int out_size, void* d_ws, size_t ws_size,
                              hipStream_t stream) {
    const int*   tok   = (const int*)d_in[0];
    const int*   lens  = (const int*)d_in[1];
    const float* h0    = (const float*)d_in[2];
    const float* c0    = (const float*)d_in[3];
    const float* embed = (const float*)d_in[4];
    const float* Wih0  = (const float*)d_in[5];
    const float* Wih1  = (const float*)d_in[6];
    const float* Whh   = (const float*)d_in[7];
    const float* bih   = (const float*)d_in[8];
    const float* bhh   = (const float*)d_in[9];
    const float* Wout  = (const float*)d_in[10];
    const float* bout  = (const float*)d_in[11];
    float* out = (float*)d_out;

    ushort_t* hb16  = (ushort_t*)d_ws;                        // [4][2][B][H] bf16
    float*    G0    = (float*)(hb16 + (size_t)4 * 2 * B * H); // [2][28][512][4] f32
    float*    bias1 = G0 + 2 * NE * FH;                       // [2][2048] f32
    int*      cnt   = (int*)(bias1 + 2 * FH);                 // [NPH][NCELL]
    int*      tokT  = cnt + NPH * NCELL;                      // [T][B]

    (void)hipFuncSetAttribute((const void*)k_persist,
                              hipFuncAttributeMaxDynamicSharedMemorySize, LDS_BYTES);

    k_init<<<(NPH * NCELL + 255) / 256, 256, 0, stream>>>(cnt);
    k_g0<<<(2 * NE * FH + 255) / 256, 256, 0, stream>>>(embed, Wih0, bih, bhh, G0, bias1);
    k_state<<<(4 * B * H + 255) / 256, 256, 0, stream>>>(h0, hb16);
    k_tokT<<<(B * T + 255) / 256, 256, 0, stream>>>(tok, tokT);
    k_len<<<1, 256, 0, stream>>>(lens, out + (size_t)B * T * NC);

    k_persist<<<NBLK, 512, LDS_BYTES, stream>>>(Whh, Wih1, G0, bias1, c0, hb16,
                                                tokT, lens, Wout, bout, out, cnt);
}

// Round 10
// 10700.156 us; speedup vs baseline: 2.5858x; 1.2063x over previous
//
#include <hip/hip_runtime.h>
#include <hip/hip_bf16.h>
#include <stdint.h>

typedef unsigned short ushort_t;
typedef unsigned char u8_t;
typedef unsigned long long u64_t;

#define H   512
#define E   128
#define NC  27
#define NE  28
#define B   256
#define T   512
#define FH  2048        // 4*H
#define NPH (T + 2)     // phases 0..T+1
#define NBLK 224        // 64 L0 + 128 L1 + 32 OUT
#define NCELL 16
#define BHs (B * H)
#define WOFF 98304      // A ring: 6 x 16KB in [0,96K); weights above
#define LDS_BYTES (147456)

typedef __bf16 bf16x8 __attribute__((ext_vector_type(8)));
typedef float  f32x4  __attribute__((ext_vector_type(4)));

#define WAITV(n) asm volatile("s_waitcnt vmcnt(" #n ")" ::: "memory")
#define LADDER(rem) do { if ((rem) >= 5) WAITV(10); else if ((rem) == 4) WAITV(8); \
                         else if ((rem) == 3) WAITV(6); else if ((rem) == 2) WAITV(4); \
                         else if ((rem) == 1) WAITV(2); else WAITV(0); } while (0)

__device__ __forceinline__ ushort_t f2b(float x) {
    uint32_t u = __float_as_uint(x);
    uint32_t r = (u + 0x7FFFu + ((u >> 16) & 1u)) >> 16;
    return (ushort_t)r;
}
// f32 -> fp8 e4m3fn, RNE, handles subnormals; inputs here are |x| <~ 4
__device__ __forceinline__ u8_t f2fp8(float x) {
    uint32_t u = __float_as_uint(x);
    uint32_t s = (u >> 24) & 0x80u;
    int E8 = (int)((u >> 23) & 0xffu);
    uint32_t M = u & 0x7fffffu;
    if (E8 == 0) return (u8_t)s;
    int e8 = E8 - 120;                      // e4m3 biased exp
    uint32_t code;
    if (e8 <= 0) {
        int sh = 1 - e8;
        if (sh > 23) return (u8_t)s;
        code = (0x800000u | M) >> sh;       // subnormal path (exp field 0)
    } else {
        code = ((uint32_t)e8 << 23) | M;
    }
    uint32_t r = (code + 0x7ffffu + ((code >> 20) & 1u)) >> 20;
    if (r > 0x7eu) r = 0x7eu;               // clamp to 448 (never NaN)
    return (u8_t)(s | r);
}
__device__ __forceinline__ float sigm(float x) {
    return 1.f / (1.f + __expf(-x));
}
// write-through agent stores — LLC-visible, no dirty L2 line
__device__ __forceinline__ void stc1(u8_t* p, u8_t v) {
    __hip_atomic_store(p, v, __ATOMIC_RELAXED, __HIP_MEMORY_SCOPE_AGENT);
}
__device__ __forceinline__ void stc2(ushort_t* p, ushort_t v) {
    __hip_atomic_store(p, v, __ATOMIC_RELAXED, __HIP_MEMORY_SCOPE_AGENT);
}
__device__ __forceinline__ void stc4f(float* p, float v) {
    __hip_atomic_store(p, v, __ATOMIC_RELAXED, __HIP_MEMORY_SCOPE_AGENT);
}
// LLC-coherent 16B load (bypasses L1/L2) — OUT-role staging
__device__ __forceinline__ bf16x8 ldc16(const ushort_t* p) {
    union { u64_t q[2]; bf16x8 v; } u;
    u.q[0] = __hip_atomic_load((const u64_t*)p,       __ATOMIC_RELAXED, __HIP_MEMORY_SCOPE_AGENT);
    u.q[1] = __hip_atomic_load(((const u64_t*)p) + 1, __ATOMIC_RELAXED, __HIP_MEMORY_SCOPE_AGENT);
    return u.v;
}
// async global->LDS, 16B/lane, CPol sc0|sc1: LLC-coherent
__device__ __forceinline__ void gload_lds16c(const void* g, void* l) {
    __builtin_amdgcn_global_load_lds(
        (const __attribute__((address_space(1))) void*)g,
        (__attribute__((address_space(3))) void*)l, 16, 0, 17);
}

// stage one fp8 A-chunk [256 rows][64 cols] = 16 KB (wave-private rows)
// LDS linear dest; source 16B-granule-swizzled: g ^= (r&3)^((r>>2)&3)
__device__ __forceinline__ void stageA8(const u8_t* __restrict__ hsrc, int k0,
                                        char* chunk, int wave, int lane) {
    int gd = lane & 3;
    #pragma unroll
    for (int i = 0; i < 2; ++i) {
        int r = wave * 32 + i * 16 + (lane >> 2);
        int fr = (r & 3) ^ ((r >> 2) & 3);
        const u8_t* g = hsrc + (size_t)r * H + k0 + ((gd ^ fr) << 4);
        gload_lds16c((const void*)g, (void*)(chunk + wave * 2048 + i * 1024));
    }
}

// ---------------- setup kernels ----------------

__global__ void k_init(int* __restrict__ cnt) {
    int i = blockIdx.x * blockDim.x + threadIdx.x;
    if (i < NPH * NCELL) cnt[i] = 0;
}

// G0 layout: [cell][token][j][gate] f32
__global__ void k_g0(const float* __restrict__ embed, const float* __restrict__ Wih0,
                     const float* __restrict__ bih, const float* __restrict__ bhh,
                     float* __restrict__ G0, float* __restrict__ bias1) {
    int i = blockIdx.x * blockDim.x + threadIdx.x;
    if (i < 2 * NE * FH) {
        int d = i / (NE * FH);
        int rem = i % (NE * FH);
        int e = rem / FH;
        int n = rem % FH;
        int g = n >> 9, j = n & 511;
        const float* er = embed + (size_t)e * E;
        const float* wr = Wih0 + ((size_t)d * FH + n) * E;
        float s = 0.f;
        #pragma unroll 8
        for (int k = 0; k < E; ++k) s += er[k] * wr[k];
        G0[(((size_t)d * NE + e) * 512 + j) * 4 + g]
            = s + bih[(size_t)d * FH + n] + bhh[(size_t)d * FH + n];
    }
    if (i < 2 * FH) bias1[i] = bih[2 * FH + i] + bhh[2 * FH + i];
}

__global__ void k_state(const float* __restrict__ h0, ushort_t* __restrict__ hb16,
                        u8_t* __restrict__ hf8) {
    int i = blockIdx.x * blockDim.x + threadIdx.x;
    if (i >= 4 * B * H) return;
    int cell = i / (B * H);
    int rem  = i % (B * H);
    hb16[((size_t)(cell * 2 + 1)) * BHs + rem] = f2b(h0[i]);   // parity 1 = step -1
    hf8 [((size_t)(cell * 2 + 1)) * BHs + rem] = f2fp8(h0[i]);
}

__global__ void k_tokT(const int* __restrict__ tok, int* __restrict__ tokT) {
    int i = blockIdx.x * blockDim.x + threadIdx.x;
    if (i < B * T) {
        int b = i / T, t = i % T;
        tokT[(size_t)t * B + b] = tok[i];
    }
}

__global__ void k_len(const int* __restrict__ lens, float* __restrict__ out_len) {
    int i = threadIdx.x;
    if (i < B) out_len[i] = (float)lens[i];
}

// ---------------- grid barrier (fence-free, r4-proven) ----------------
__device__ __forceinline__ void gbar(int* cnt, int p) {
    __syncthreads();        // drains all vmem incl. agent h-stores
    if (threadIdx.x == 0) {
        int* base = cnt + p * NCELL;
        __hip_atomic_fetch_add(base + (blockIdx.x & (NCELL - 1)), 1,
                               __ATOMIC_RELAXED, __HIP_MEMORY_SCOPE_AGENT);
        int total;
        do {
            total = 0;
            #pragma unroll
            for (int c2 = 0; c2 < NCELL; ++c2)
                total += __hip_atomic_load(base + c2, __ATOMIC_RELAXED, __HIP_MEMORY_SCOPE_AGENT);
            if (total < NBLK) __builtin_amdgcn_s_sleep(2);
        } while (total < NBLK);
    }
    __syncthreads();
    __builtin_amdgcn_sched_barrier(0);
}

// Phase p: L0 step t=p (p<T); L1 step s=p-1 (1<=p<=T); OUT logits t2=p-2 (p>=2).
// hf8/hb16: [cell][parity][B][H], parity(step)=step&1.
__global__ __launch_bounds__(512, 2) void k_persist(
    const float* __restrict__ Whh, const float* __restrict__ Wih1,
    const float* __restrict__ G0, const float* __restrict__ bias1,
    const float* __restrict__ c0, ushort_t* __restrict__ hb16,
    u8_t* __restrict__ hf8,
    const int* __restrict__ tokT, const int* __restrict__ lens,
    const float* __restrict__ Wout, const float* __restrict__ bout,
    float* __restrict__ out, int* __restrict__ cnt)
{
    extern __shared__ char smem[];
    const int bid = blockIdx.x;
    const int tid = threadIdx.x;
    const int lane = tid & 63, wave = tid >> 6;
    const int lrow = lane & 15, kg = lane >> 4;
    const int row0 = wave * 32;
    const int sw8 = lrow & 7;
    // fp8 A-read addressing (matches stageA8 source swizzle)
    const int fA = (lrow & 3) ^ ((lrow >> 2) & 3);
    int aoffK[2];
    #pragma unroll
    for (int ks = 0; ks < 2; ++ks)
        aoffK[ks] = (row0 + lrow) * 64 + ((((ks << 1) | (kg >> 1)) ^ fA) << 4) + ((kg & 1) << 3);
    int wksoff[2];
    #pragma unroll
    for (int ks = 0; ks < 2; ++ks)
        wksoff[ks] = (((ks * 4 + kg) ^ sw8) << 3);

    // ---- one-time: stage weights into LDS (f32 -> fp8, slot-swizzled) ----
    if (bid < 64) {
        const int cell = bid >> 5, jt = bid & 31, j0 = jt * 16;
        const float* Wsrc = Whh + (size_t)cell * FH * H;
        for (int r = wave; r < 64; r += 8) {
            int grow = (r >> 4) * 512 + j0 + (r & 15);
            const float* src = Wsrc + (size_t)grow * H;
            for (int c = lane; c < H; c += 64) {
                int slot = c >> 3;
                int ssw = (slot & ~7) | ((slot ^ r) & 7);
                *(u8_t*)(smem + WOFF + r * 512 + ssw * 8 + (c & 7)) = f2fp8(src[c]);
            }
        }
    } else if (bid < 192) {
        const int q = bid - 64, cell = 2 + (q >> 6), jt = q & 63, j0 = jt * 8;
        const float* Wi = Wih1 + (size_t)(cell - 2) * FH * (2 * H);
        const float* Wh = Whh + (size_t)cell * FH * H;
        for (int r = wave; r < 32; r += 8) {
            int grow = (r >> 3) * 512 + j0 + (r & 7);
            const float* si = Wi + (size_t)grow * (2 * H);
            const float* sh = Wh + (size_t)grow * H;
            for (int c = lane; c < 1536; c += 64) {
                float v = (c < 1024) ? si[c] : sh[c - 1024];
                int slot = c >> 3;
                int ssw = (slot & ~7) | ((slot ^ r) & 7);
                *(u8_t*)(smem + WOFF + r * 1536 + ssw * 8 + (c & 7)) = f2fp8(v);
            }
        }
    } else {
        for (int r = wave; r < NC; r += 8) {
            const float* src = Wout + (size_t)r * (2 * H);
            int sw = (r & 7) << 4;
            for (int c = lane; c < 2 * H; c += 64) {
                int byte = ((r * (2 * H) + c) * 2) ^ sw;
                *(ushort_t*)(smem + byte) = f2b(src[c]);
            }
        }
    }
    __syncthreads();

    if (bid < 64) {
        // ================= layer 0 (fp8 GEMM) =================
        const int cell = bid >> 5, jt = bid & 31, j0 = jt * 16;
        const int j = j0 + lrow;
        int wgbase[4];
        #pragma unroll
        for (int g = 0; g < 4; ++g) wgbase[g] = WOFF + (g * 16 + lrow) * 512;

        float cv[8];
        #pragma unroll
        for (int i = 0; i < 8; ++i) {
            int bb = row0 + (i >> 2) * 16 + kg * 4 + (i & 3);
            cv[i] = c0[((size_t)cell * B + bb) * H + j];
        }
        f32x4 g0v[8];
        #pragma unroll
        for (int i = 0; i < 8; ++i) {
            int bb = row0 + (i >> 2) * 16 + kg * 4 + (i & 3);
            int tk = tokT[bb];
            g0v[i] = *(const f32x4*)(G0 + (((size_t)cell * NE + tk) * 512 + j) * 4);
        }

        for (int p = 0; p < NPH; ++p) {
            if (p < T) {
                const int parR = (p + 1) & 1, parW = p & 1;
                const u8_t* hsrc = hf8 + (size_t)(cell * 2 + parR) * BHs;

                #pragma unroll
                for (int c2 = 0; c2 < 6; ++c2)
                    stageA8(hsrc, c2 * 64, smem + c2 * 16384, wave, lane);

                f32x4 acc[2][4];
                #pragma unroll
                for (int m = 0; m < 2; ++m)
                    #pragma unroll
                    for (int g = 0; g < 4; ++g) acc[m][g] = (f32x4){0.f, 0.f, 0.f, 0.f};

                #pragma unroll
                for (int t = 0; t < 8; ++t) {
                    LADDER(7 - t);
                    __builtin_amdgcn_sched_barrier(0);
                    const char* Ab = smem + (t % 6) * 16384;
                    u64_t aA[2][2], wW[2][4];
                    #pragma unroll
                    for (int ks = 0; ks < 2; ++ks) {
                        aA[ks][0] = *(const u64_t*)(Ab + aoffK[ks]);
                        aA[ks][1] = *(const u64_t*)(Ab + aoffK[ks] + 1024);
                        #pragma unroll
                        for (int g = 0; g < 4; ++g)
                            wW[ks][g] = *(const u64_t*)(smem + wgbase[g] + t * 64 + wksoff[ks]);
                    }
                    asm volatile("s_waitcnt lgkmcnt(0)" ::: "memory");
                    __builtin_amdgcn_sched_barrier(0);
                    if (t + 6 < 8) stageA8(hsrc, (t + 6) * 64, smem + (t % 6) * 16384, wave, lane);
                    __builtin_amdgcn_sched_barrier(0);
                    #pragma unroll
                    for (int ks = 0; ks < 2; ++ks)
                        #pragma unroll
                        for (int g = 0; g < 4; ++g) {
                            acc[0][g] = __builtin_amdgcn_mfma_f32_16x16x32_fp8_fp8(
                                (long)aA[ks][0], (long)wW[ks][g], acc[0][g], 0, 0, 0);
                            acc[1][g] = __builtin_amdgcn_mfma_f32_16x16x32_fp8_fp8(
                                (long)aA[ks][1], (long)wW[ks][g], acc[1][g], 0, 0, 0);
                        }
                }

                #pragma unroll
                for (int i = 0; i < 8; ++i) {
                    int mf = i >> 2, r = i & 3;
                    int bb = row0 + mf * 16 + kg * 4 + r;
                    float gi = acc[mf][0][r] + g0v[i][0];
                    float gf = acc[mf][1][r] + g0v[i][1];
                    float gg = acc[mf][2][r] + g0v[i][2];
                    float go = acc[mf][3][r] + g0v[i][3];
                    float ii = sigm(gi), ff = sigm(gf), oo = sigm(go);
                    float tg = tanhf(gg);
                    float cn = ff * cv[i] + ii * tg;
                    cv[i] = cn;
                    float hn = oo * tanhf(cn);
                    stc1(&hf8[((size_t)(cell * 2 + parW) * B + bb) * H + j], f2fp8(hn));
                }
                if (p + 1 < T) {
                    #pragma unroll
                    for (int i = 0; i < 8; ++i) {
                        int bb = row0 + (i >> 2) * 16 + kg * 4 + (i & 3);
                        int tk = tokT[(size_t)(p + 1) * B + bb];
                        g0v[i] = *(const f32x4*)(G0 + (((size_t)cell * NE + tk) * 512 + j) * 4);
                    }
                }
            }
            if (p < NPH - 1) gbar(cnt, p);
        }
    } else if (bid < 192) {
        // ================= layer 1 (fp8 GEMM) =================
        const int q = bid - 64, cell = 2 + (q >> 6), jt = q & 63, j0 = jt * 8;
        const int cc = lrow;
        const int jj = j0 + (cc & 7);
        const int mfS = cc >> 3;
        int wnbase[2];
        #pragma unroll
        for (int nf = 0; nf < 2; ++nf) wnbase[nf] = WOFF + (nf * 16 + lrow) * 1536;

        float b1v[4];
        #pragma unroll
        for (int g = 0; g < 4; ++g) b1v[g] = bias1[(size_t)(cell - 2) * FH + g * 512 + jj];

        float cv[4];
        #pragma unroll
        for (int r = 0; r < 4; ++r) {
            int bb = row0 + mfS * 16 + kg * 4 + r;
            cv[r] = c0[((size_t)cell * B + bb) * H + jj];
        }

        for (int p = 0; p < NPH; ++p) {
            if (p >= 1 && p <= T) {
                const int parY  = (p + 1) & 1;
                const int parR2 = p & 1;
                const int parW  = (p + 1) & 1;
                const u8_t* base0 = hf8 + (size_t)(0 * 2 + parY) * BHs;
                const u8_t* base1 = hf8 + (size_t)(2 + parY) * BHs;
                const u8_t* base2 = hf8 + (size_t)(cell * 2 + parR2) * BHs;

                #pragma unroll
                for (int c2 = 0; c2 < 6; ++c2)
                    stageA8(base0, c2 * 64, smem + c2 * 16384, wave, lane);

                f32x4 acc[2][2];
                #pragma unroll
                for (int m = 0; m < 2; ++m)
                    #pragma unroll
                    for (int n = 0; n < 2; ++n) acc[m][n] = (f32x4){0.f, 0.f, 0.f, 0.f};

                #pragma unroll
                for (int t = 0; t < 24; ++t) {
                    LADDER(23 - t);
                    __builtin_amdgcn_sched_barrier(0);
                    const char* Ab = smem + (t % 6) * 16384;
                    u64_t aA[2][2], wW[2][2];
                    #pragma unroll
                    for (int ks = 0; ks < 2; ++ks) {
                        aA[ks][0] = *(const u64_t*)(Ab + aoffK[ks]);
                        aA[ks][1] = *(const u64_t*)(Ab + aoffK[ks] + 1024);
                        #pragma unroll
                        for (int nf = 0; nf < 2; ++nf)
                            wW[ks][nf] = *(const u64_t*)(smem + wnbase[nf] + t * 64 + wksoff[ks]);
                    }
                    asm volatile("s_waitcnt lgkmcnt(0)" ::: "memory");
                    __builtin_amdgcn_sched_barrier(0);
                    if (t + 6 < 24) {
                        int c2 = t + 6;
                        const u8_t* src = (c2 < 8) ? base0 : (c2 < 16) ? base1 : base2;
                        stageA8(src, (c2 & 7) * 64, smem + (t % 6) * 16384, wave, lane);
                    }
                    __builtin_amdgcn_sched_barrier(0);
                    #pragma unroll
                    for (int ks = 0; ks < 2; ++ks) {
                        acc[0][0] = __builtin_amdgcn_mfma_f32_16x16x32_fp8_fp8(
                            (long)aA[ks][0], (long)wW[ks][0], acc[0][0], 0, 0, 0);
                        acc[0][1] = __builtin_amdgcn_mfma_f32_16x16x32_fp8_fp8(
                            (long)aA[ks][0], (long)wW[ks][1], acc[0][1], 0, 0, 0);
                        acc[1][0] = __builtin_amdgcn_mfma_f32_16x16x32_fp8_fp8(
                            (long)aA[ks][1], (long)wW[ks][0], acc[1][0], 0, 0, 0);
                        acc[1][1] = __builtin_amdgcn_mfma_f32_16x16x32_fp8_fp8(
                            (long)aA[ks][1], (long)wW[ks][1], acc[1][1], 0, 0, 0);
                    }
                }

                #pragma unroll
                for (int r = 0; r < 4; ++r) {
                    float a00 = acc[0][0][r], a01 = acc[0][1][r];
                    float a10 = acc[1][0][r], a11 = acc[1][1][r];
                    float e00 = __shfl_xor(a00, 8);
                    float e01 = __shfl_xor(a01, 8);
                    float e10 = __shfl_xor(a10, 8);
                    float e11 = __shfl_xor(a11, 8);
                    float gi, gf, gg, go;
                    if (mfS == 0) { gi = a00; gf = e00; gg = a01; go = e01; }
                    else          { gi = e10; gf = a10; gg = e11; go = a11; }
                    gi += b1v[0]; gf += b1v[1]; gg += b1v[2]; go += b1v[3];
                    int bb = row0 + mfS * 16 + kg * 4 + r;
                    float ii = sigm(gi), ff = sigm(gf), oo = sigm(go);
                    float tg = tanhf(gg);
                    float cn = ff * cv[r] + ii * tg;
                    cv[r] = cn;
                    float hn = oo * tanhf(cn);
                    size_t hi = ((size_t)(cell * 2 + parW) * B + bb) * H + jj;
                    stc1(&hf8[hi], f2fp8(hn));
                    stc2(&hb16[hi], f2b(hn));      // bf16 copy for OUT role
                }
            }
            if (p < NPH - 1) gbar(cnt, p);
        }
    } else {
        // ================= logits (bf16 path, unchanged) =================
        const int b = (bid - 192) * 8 + wave;
        const int c = lane & 31, kh = lane >> 5;
        const int half = lane >> 5, qq = lane & 31;
        const int sww = (c & 7) << 4;
        const int rowbase = c * 2048;
        const int lenb = lens[b];
        const float bo = (c < NC) ? bout[c] : 0.f;
        char* scr = smem + 57344 + wave * 2048;

        for (int p = 0; p < NPH; ++p) {
            if (p >= 2) {
                const int t2 = p - 2, parL = p & 1;
                {
                    const ushort_t* src = hb16 + (size_t)((2 + half) * 2 + parL) * BHs
                                        + (size_t)b * H + qq * 16;
                    bf16x8 v0 = ldc16(src);
                    bf16x8 v1 = ldc16(src + 8);
                    char* dst = scr + half * 1024 + qq * 32;
                    *(bf16x8*)dst = v0;
                    *(bf16x8*)(dst + 16) = v1;
                }
                __syncthreads();
                float sum = 0.f;
                if (c < NC) {
                    const char* ybase = scr + kh * 1024;
                    #pragma unroll 8
                    for (int t = 0; t < 64; ++t) {
                        bf16x8 v = *(const bf16x8*)(ybase + t * 16);
                        bf16x8 w = *(const bf16x8*)(smem + rowbase + ((kh * 1024 + t * 16) ^ sww));
                        #pragma unroll
                        for (int i = 0; i < 8; ++i) sum += (float)v[i] * (float)w[i];
                    }
                }
                sum += __shfl_xor(sum, 32);
                if (kh == 0 && c < NC) {
                    float val = (t2 < lenb) ? (sum + bo) : 0.f;
                    stc4f(&out[((size_t)b * T + t2) * NC + c], val);
                }
            }
            if (p < NPH - 1) gbar(cnt, p);
        }
    }
}

// ---------------- launch ----------------

extern "C" void kernel_launch(void* const* d_in, const int* in_sizes, int n_in,
                              void* d_out, int out_size, void* d_ws, size_t ws_size,
                              hipStream_t stream) {
    const int*   tok   = (const int*)d_in[0];
    const int*   lens  = (const int*)d_in[1];
    const float* h0    = (const float*)d_in[2];
    const float* c0    = (const float*)d_in[3];
    const float* embed = (const float*)d_in[4];
    const float* Wih0  = (const float*)d_in[5];
    const float* Wih1  = (const float*)d_in[6];
    const float* Whh   = (const float*)d_in[7];
    const float* bih   = (const float*)d_in[8];
    const float* bhh   = (const float*)d_in[9];
    const float* Wout  = (const float*)d_in[10];
    const float* bout  = (const float*)d_in[11];
    float* out = (float*)d_out;

    ushort_t* hb16  = (ushort_t*)d_ws;                        // [4][2][B][H] bf16, 2MB
    u8_t*     hf8   = (u8_t*)(hb16 + (size_t)4 * 2 * B * H);  // [4][2][B][H] fp8, 1MB
    float*    G0    = (float*)(hf8 + (size_t)4 * 2 * B * H);  // [2][28][512][4] f32
    float*    bias1 = G0 + 2 * NE * FH;                       // [2][2048] f32
    int*      cnt   = (int*)(bias1 + 2 * FH);                 // [NPH][NCELL]
    int*      tokT  = cnt + NPH * NCELL;                      // [T][B]

    (void)hipFuncSetAttribute((const void*)k_persist,
                              hipFuncAttributeMaxDynamicSharedMemorySize, LDS_BYTES);

    k_init<<<(NPH * NCELL + 255) / 256, 256, 0, stream>>>(cnt);
    k_g0<<<(2 * NE * FH + 255) / 256, 256, 0, stream>>>(embed, Wih0, bih, bhh, G0, bias1);
    k_state<<<(4 * B * H + 255) / 256, 256, 0, stream>>>(h0, hb16, hf8);
    k_tokT<<<(B * T + 255) / 256, 256, 0, stream>>>(tok, tokT);
    k_len<<<1, 256, 0, stream>>>(lens, out + (size_t)B * T * NC);

    k_persist<<<NBLK, 512, LDS_BYTES, stream>>>(Whh, Wih1, G0, bias1, c0, hb16, hf8,
                                                tokT, lens, Wout, bout, out, cnt);
}